// Round 10
// baseline (2918.083 us; speedup 1.0000x reference)
//
#include <hip/hip_runtime.h>
#include <math.h>

namespace {

typedef __fp16 half2v __attribute__((ext_vector_type(2)));
static_assert(sizeof(half2v) == 4, "half2v must be 32-bit");

constexpr int T = 4096, NB = 256, I = 64, H = 256, O = 64;
// h stored as i8[256] = 64 words, padded: word W -> idx (W>>3)*12 + (W&7).
constexpr int HWORDS = 96;                  // 8 groups * 12
constexpr float WSCALE = 2032.f;            // |w| <= 1/16 -> |q| <= 127
constexpr float CH = 1.f / (127.f * 2032.f);

__device__ __forceinline__ half2v pkrtz(float a, float b) {
  return __builtin_bit_cast(half2v, __builtin_amdgcn_cvt_pkrtz(a, b));
}
__device__ __forceinline__ float fdot2(half2v a, half2v b, float c) {
  typedef _Float16 fdot_t __attribute__((ext_vector_type(2)));
  return __builtin_amdgcn_fdot2(__builtin_bit_cast(fdot_t, a),
                                __builtin_bit_cast(fdot_t, b), c, false);
}

#if defined(__has_builtin)
#if __has_builtin(__builtin_amdgcn_sdot4)
#define SDOT4_BUILTIN 1
#endif
#endif
__device__ __forceinline__ int sdot4(int a, int b, int c) {
#ifdef SDOT4_BUILTIN
  return __builtin_amdgcn_sdot4(a, b, c, false);
#else
#pragma unroll
  for (int i = 0; i < 4; ++i)
    c += (int)(signed char)(a >> (8 * i)) * (int)(signed char)(b >> (8 * i));
  return c;
#endif
}

// BUILTIN DPP only (R6 lesson: inline-asm DPP chains violate wait-state rules).
template <int CTRL>
__device__ __forceinline__ float rorf(float v) {
  int r = __builtin_amdgcn_update_dpp(0, __float_as_int(v), CTRL, 0xF, 0xF, true);
  return v + __int_as_float(r);
}
__device__ __forceinline__ float red16f(float v) {
  v = rorf<0x121>(v); v = rorf<0x122>(v); v = rorf<0x124>(v); v = rorf<0x128>(v);
  return v;
}
template <int CTRL>
__device__ __forceinline__ int rori(int v) {
  return v + __builtin_amdgcn_update_dpp(0, v, CTRL, 0xF, 0xF, true);
}
__device__ __forceinline__ int red16i(int v) {
  v = rori<0x121>(v); v = rori<0x122>(v); v = rori<0x124>(v); v = rori<0x128>(v);
  return v;
}

__device__ __forceinline__ int qpack(float4 v) {
  int q0 = (int)rintf(v.x * WSCALE) & 255;
  int q1 = (int)rintf(v.y * WSCALE) & 255;
  int q2 = (int)rintf(v.z * WSCALE) & 255;
  int q3 = (int)rintf(v.w * WSCALE) & 255;
  return q0 | (q1 << 8) | (q2 << 16) | (q3 << 24);
}
__device__ __forceinline__ int widx(int W) { return (W >> 3) * 12 + (W & 7); }

// 1024 threads/block, one block per batch row, one barrier per step.
// kq = tid&15 owns h-dims [16kq,16kq+16) (4 i8 words) and x-dims [4kq,4kq+4).
// jg = tid>>4 owns h-rows 4jg..4jg+3 and y-row jg.
// Weights: whh 16 i8-words + who 4 i8-words + wih 8 half2 = 28 regs resident.
__global__ __launch_bounds__(1024) void rnn_fused(
    const float* __restrict__ xin,   // [T,NB,I]
    const float* __restrict__ Wih,   // [H,I]
    const float* __restrict__ Whh,   // [H,H]
    const float* __restrict__ Who,   // [O,H]
    float* __restrict__ out)         // [T*NB*O] ++ [NB*H]
{
  const int b   = blockIdx.x;
  const int tid = threadIdx.x;
  const int kq  = tid & 15;
  const int jg  = tid >> 4;
  const bool kb1 = (kq & 1) != 0;
  const bool kb2 = (kq & 2) != 0;

  __shared__ __align__(16) uint32_t hbuf[2][HWORDS];

  // ---- resident weights ----
  int whhq[4][4];
#pragma unroll
  for (int r = 0; r < 4; ++r) {
    const float* src = Whh + (size_t)(jg * 4 + r) * H + kq * 16;
#pragma unroll
    for (int c = 0; c < 4; ++c)
      whhq[r][c] = qpack(*reinterpret_cast<const float4*>(src + 4 * c));
  }
  int whoq[4];
  {
    const float* src = Who + (size_t)jg * H + kq * 16;
#pragma unroll
    for (int c = 0; c < 4; ++c)
      whoq[c] = qpack(*reinterpret_cast<const float4*>(src + 4 * c));
  }
  half2v wihp[8];
#pragma unroll
  for (int r = 0; r < 4; ++r) {
    float4 v = *reinterpret_cast<const float4*>(Wih + (size_t)(jg * 4 + r) * I + kq * 4);
    wihp[r * 2]     = pkrtz(v.x, v.y);
    wihp[r * 2 + 1] = pkrtz(v.z, v.w);
  }

  // ---- init ----
  if (tid < HWORDS) hbuf[0][tid] = 0u;               // h(-1) = 0
  const float* xg = xin + (size_t)b * I + kq * 4;    // + t*16384 floats
  float4 xrA = *reinterpret_cast<const float4*>(xg); // x(0)
  float4 xrB;
  const int rdoff = 12 * (kq >> 1) + 4 * (kq & 1);   // idx of words 4kq..4kq+3
  const int wbyte = widx(jg) * 4 + kq;               // byte of h[4jg+kq], kq<4
  const int ybase = b * O + jg;
  __syncthreads();

#define STEP(SRC, DST, TCUR, XCUR, XNXT, TPRE)                                   \
  {                                                                              \
    const uint4 hk_ = *reinterpret_cast<const uint4*>((SRC) + rdoff);            \
    XNXT = *reinterpret_cast<const float4*>(xg + ((size_t)(TPRE) << 14));        \
    half2v xp0_ = pkrtz(XCUR.x, XCUR.y);                                         \
    half2v xp1_ = pkrtz(XCUR.z, XCUR.w);                                         \
    float f0_ = fdot2(xp1_, wihp[1], fdot2(xp0_, wihp[0], 0.f));                 \
    float f1_ = fdot2(xp1_, wihp[3], fdot2(xp0_, wihp[2], 0.f));                 \
    float f2_ = fdot2(xp1_, wihp[5], fdot2(xp0_, wihp[4], 0.f));                 \
    float f3_ = fdot2(xp1_, wihp[7], fdot2(xp0_, wihp[6], 0.f));                 \
    int i0_ = sdot4(hk_.w, whhq[0][3], sdot4(hk_.z, whhq[0][2],                  \
              sdot4(hk_.y, whhq[0][1], sdot4(hk_.x, whhq[0][0], 0))));           \
    int i1_ = sdot4(hk_.w, whhq[1][3], sdot4(hk_.z, whhq[1][2],                  \
              sdot4(hk_.y, whhq[1][1], sdot4(hk_.x, whhq[1][0], 0))));           \
    int i2_ = sdot4(hk_.w, whhq[2][3], sdot4(hk_.z, whhq[2][2],                  \
              sdot4(hk_.y, whhq[2][1], sdot4(hk_.x, whhq[2][0], 0))));           \
    int i3_ = sdot4(hk_.w, whhq[3][3], sdot4(hk_.z, whhq[3][2],                  \
              sdot4(hk_.y, whhq[3][1], sdot4(hk_.x, whhq[3][0], 0))));           \
    int iy_ = sdot4(hk_.w, whoq[3], sdot4(hk_.z, whoq[2],                        \
              sdot4(hk_.y, whoq[1], sdot4(hk_.x, whoq[0], 0))));                 \
    float s0_ = red16f(fmaf((float)i0_, CH, f0_));                               \
    float s1_ = red16f(fmaf((float)i1_, CH, f1_));                               \
    float s2_ = red16f(fmaf((float)i2_, CH, f2_));                               \
    float s3_ = red16f(fmaf((float)i3_, CH, f3_));                               \
    iy_ = red16i(iy_);                                                           \
    float sA_ = kb1 ? s1_ : s0_;                                                 \
    float sB_ = kb1 ? s3_ : s2_;                                                 \
    float s_  = kb2 ? sB_ : sA_;                                                 \
    float e_  = __builtin_amdgcn_exp2f(s_ * 2.885390081777927f);                 \
    float rc_ = __builtin_amdgcn_rcpf(e_ + 1.f);                                 \
    int   hq_ = (int)rintf(fmaf(-254.f, rc_, 127.f));                            \
    if (kq < 4)                                                                  \
      reinterpret_cast<char*>(DST)[wbyte] = (char)hq_;                           \
    if (kq == 0 && (TCUR) > 0)                                                   \
      out[((size_t)((TCUR) - 1) << 14) + ybase] = (float)iy_ * CH;               \
    asm volatile("s_waitcnt lgkmcnt(0)\n\ts_barrier" ::: "memory");              \
  }

  for (int t = 0; t < T; t += 2) {
    const int tp = (t + 3 < T) ? (t + 2) : (T - 1);
    STEP(hbuf[0], hbuf[1], t, xrA, xrB, t + 1);
    STEP(hbuf[1], hbuf[0], t + 1, xrB, xrA, tp);
  }
#undef STEP

  // ---- epilogue: y(T-1) from h(T-1) in hbuf[0] ----
  {
    const uint4 hk = *reinterpret_cast<const uint4*>(&hbuf[0][rdoff]);
    int iy = sdot4(hk.w, whoq[3], sdot4(hk.z, whoq[2],
             sdot4(hk.y, whoq[1], sdot4(hk.x, whoq[0], 0))));
    iy = red16i(iy);
    if (kq == 0) out[((size_t)(T - 1) << 14) + ybase] = (float)iy * CH;
  }
  // ---- h_last (fp32) ----
  if (tid < H) {
    uint32_t w = hbuf[0][widx(tid >> 2)];
    int q = (int)(signed char)((w >> (8 * (tid & 3))) & 255u);
    out[(size_t)T * NB * O + (size_t)b * H + tid] = (float)q * (1.f / 127.f);
  }
}

}  // namespace

extern "C" void kernel_launch(void* const* d_in, const int* in_sizes, int n_in,
                              void* d_out, int out_size, void* d_ws, size_t ws_size,
                              hipStream_t stream) {
  const float* xin = (const float*)d_in[0];
  const float* Wih = (const float*)d_in[1];
  const float* Whh = (const float*)d_in[2];
  const float* Who = (const float*)d_in[3];
  float* out = (float*)d_out;
  hipLaunchKernelGGL(rnn_fused, dim3(NB), dim3(1024), 0, stream,
                     xin, Wih, Whh, Who, out);
}

// Round 11
// 2810.063 us; speedup vs baseline: 1.0384x; 1.0384x over previous
//
#include <hip/hip_runtime.h>
#include <math.h>

namespace {

typedef _Float16 f16x8 __attribute__((ext_vector_type(8)));
typedef float    f32x4 __attribute__((ext_vector_type(4)));
typedef unsigned int u32;

constexpr int T = 4096, NB = 256, I = 64, H = 256, O = 64;

__device__ __forceinline__ u32 pkw(float a, float b) {
  return __builtin_bit_cast(u32, __builtin_amdgcn_cvt_pkrtz(a, b));
}
__device__ __forceinline__ f32x4 MFMA(uint4 a, uint4 b, f32x4 c) {
  return __builtin_amdgcn_mfma_f32_16x16x32_f16(
      __builtin_bit_cast(f16x8, a), __builtin_bit_cast(f16x8, b), c, 0, 0, 0);
}
__device__ __forceinline__ float tanh_fast(float s) {
  float e = __builtin_amdgcn_exp2f(s * 2.8853900817779268f);
  return fmaf(-2.f, __builtin_amdgcn_rcpf(e + 1.f), 1.f);
}
__device__ __forceinline__ uint4 mkfrag(const float* p) {
  float4 u = *reinterpret_cast<const float4*>(p);
  float4 v = *reinterpret_cast<const float4*>(p + 4);
  uint4 r;
  r.x = pkw(u.x, u.y); r.y = pkw(u.z, u.w);
  r.z = pkw(v.x, v.y); r.w = pkw(v.z, v.w);
  return r;
}

// One block (512 thr = 8 waves) per batch row; one barrier per step.
// GEMV via MFMA 16x16x32 f16 with h replicated across all 16 B-columns:
// every lane's 4 C-regs hold rows (lg*4 + r) of its M-tile -> no cross-lane
// reduce, no DPP, K accumulated inside the matrix pipe. Weight fragments
// stay resident (MFMA reads VGPR or AGPR operands natively, so AGPR
// parking is harmless here, unlike R2-R10's VALU formulations).
// Wave w owns hh/ih M-tiles {2w, 2w+1}; waves 4..7 own y M-tile (w-4).
__global__ __launch_bounds__(512) void rnn_mfma(
    const float* __restrict__ xin,   // [T,NB,I]
    const float* __restrict__ Wih,   // [H,I]
    const float* __restrict__ Whh,   // [H,H]
    const float* __restrict__ Who,   // [O,H]
    float* __restrict__ out)         // [T*NB*O] ++ [NB*H]
{
  const int b    = blockIdx.x;
  const int tid  = threadIdx.x;
  const int w    = tid >> 6;
  const int lane = tid & 63;
  const int lg   = lane >> 4;   // k-octet group (A/B) and row-quad (C)
  const int li   = lane & 15;   // A-row / B-col index

  __shared__ __align__(16) u32 hbuf[2][128];   // 2 x 256 fp16

  // ---- resident weight fragments ----
  uint4 whhf[2][8], wihf[2][2], whof[8];
#pragma unroll
  for (int mt = 0; mt < 2; ++mt) {
    const int row = (w * 2 + mt) * 16 + li;
#pragma unroll
    for (int kt = 0; kt < 8; ++kt)
      whhf[mt][kt] = mkfrag(Whh + (size_t)row * H + kt * 32 + lg * 8);
#pragma unroll
    for (int kt = 0; kt < 2; ++kt)
      wihf[mt][kt] = mkfrag(Wih + (size_t)row * I + kt * 32 + lg * 8);
  }
  if (w >= 4) {
    const int ro = (w - 4) * 16 + li;
#pragma unroll
    for (int kt = 0; kt < 8; ++kt)
      whof[kt] = mkfrag(Who + (size_t)ro * H + kt * 32 + lg * 8);
  }

  // ---- init: h(-1) = 0; load x(0) ----
  if (tid < 128) hbuf[0][tid] = 0u;
  const float* xb = xin + (size_t)b * I;
  float4 xc0, xc1, xc2, xc3;
  xc0 = *reinterpret_cast<const float4*>(xb + lg * 8);
  xc1 = *reinterpret_cast<const float4*>(xb + lg * 8 + 4);
  xc2 = *reinterpret_cast<const float4*>(xb + 32 + lg * 8);
  xc3 = *reinterpret_cast<const float4*>(xb + 32 + lg * 8 + 4);
  const size_t OUTH = (size_t)T * NB * O;
  const f32x4 z = {0.f, 0.f, 0.f, 0.f};
  __syncthreads();

  int p = 0;
  for (int t = 0; t < T; ++t) {
    // x fragments for step t (from last iteration's prefetch)
    uint4 xf0, xf1;
    xf0.x = pkw(xc0.x, xc0.y); xf0.y = pkw(xc0.z, xc0.w);
    xf0.z = pkw(xc1.x, xc1.y); xf0.w = pkw(xc1.z, xc1.w);
    xf1.x = pkw(xc2.x, xc2.y); xf1.y = pkw(xc2.z, xc2.w);
    xf1.z = pkw(xc3.x, xc3.y); xf1.w = pkw(xc3.z, xc3.w);

    // prefetch x(t+1); barrier below is lgkm-only so these float freely
    if (t + 1 < T) {
      const float* xp = xin + (size_t)(t + 1) * (NB * I) + (size_t)b * I;
      xc0 = *reinterpret_cast<const float4*>(xp + lg * 8);
      xc1 = *reinterpret_cast<const float4*>(xp + lg * 8 + 4);
      xc2 = *reinterpret_cast<const float4*>(xp + 32 + lg * 8);
      xc3 = *reinterpret_cast<const float4*>(xp + 32 + lg * 8 + 4);
    }

    // h(t-1) B-fragments: broadcast reads (4 distinct 16B addrs per wave)
    uint4 hf[8];
#pragma unroll
    for (int kt = 0; kt < 8; ++kt)
      hf[kt] = *reinterpret_cast<const uint4*>(&hbuf[p][(kt * 4 + lg) * 4]);

    // ---- matrix pipe: s = Wih x(t) + Whh h(t-1); ay = Who h(t-1) ----
    f32x4 a0 = MFMA(wihf[0][0], xf0, z);
    a0 = MFMA(wihf[0][1], xf1, a0);
    f32x4 a1 = MFMA(wihf[1][0], xf0, z);
    a1 = MFMA(wihf[1][1], xf1, a1);
    f32x4 ay = z;
#pragma unroll
    for (int kt = 0; kt < 8; ++kt) {
      a0 = MFMA(whhf[0][kt], hf[kt], a0);
      a1 = MFMA(whhf[1][kt], hf[kt], a1);
    }
    if (w >= 4) {
#pragma unroll
      for (int kt = 0; kt < 8; ++kt) ay = MFMA(whof[kt], hf[kt], ay);
    }

    // ---- epilogue: tanh + h store; y(t-1) store ----
    float t00 = tanh_fast(a0[0]), t01 = tanh_fast(a0[1]);
    float t02 = tanh_fast(a0[2]), t03 = tanh_fast(a0[3]);
    float t10 = tanh_fast(a1[0]), t11 = tanh_fast(a1[1]);
    float t12 = tanh_fast(a1[2]), t13 = tanh_fast(a1[3]);
    if (li == 0) {
      uint2 w0; w0.x = pkw(t00, t01); w0.y = pkw(t02, t03);
      uint2 w1; w1.x = pkw(t10, t11); w1.y = pkw(t12, t13);
      *reinterpret_cast<uint2*>(&hbuf[p ^ 1][(w * 2 + 0) * 8 + lg * 2]) = w0;
      *reinterpret_cast<uint2*>(&hbuf[p ^ 1][(w * 2 + 1) * 8 + lg * 2]) = w1;
      if (t == T - 1) {  // h_last in f32, straight from the accumulators
        float4 hl0 = make_float4(t00, t01, t02, t03);
        float4 hl1 = make_float4(t10, t11, t12, t13);
        *reinterpret_cast<float4*>(out + OUTH + (size_t)b * H + (w * 2 + 0) * 16 + lg * 4) = hl0;
        *reinterpret_cast<float4*>(out + OUTH + (size_t)b * H + (w * 2 + 1) * 16 + lg * 4) = hl1;
      }
    }
    if (w >= 4 && li == 0 && t > 0) {
      float4 yv = make_float4(ay[0], ay[1], ay[2], ay[3]);
      *reinterpret_cast<float4*>(out + (size_t)(t - 1) * (NB * O) +
                                 (size_t)b * O + (w - 4) * 16 + lg * 4) = yv;
    }

    // lgkm-only barrier: LDS ordered, global x-loads/y-stores stay in flight
    asm volatile("s_waitcnt lgkmcnt(0)\n\ts_barrier" ::: "memory");
    p ^= 1;
  }

  // ---- y(T-1) from h(T-1) in hbuf[p] ----
  if (w >= 4) {
    uint4 hf[8];
#pragma unroll
    for (int kt = 0; kt < 8; ++kt)
      hf[kt] = *reinterpret_cast<const uint4*>(&hbuf[p][(kt * 4 + lg) * 4]);
    f32x4 ay = z;
#pragma unroll
    for (int kt = 0; kt < 8; ++kt) ay = MFMA(whof[kt], hf[kt], ay);
    if (li == 0) {
      float4 yv = make_float4(ay[0], ay[1], ay[2], ay[3]);
      *reinterpret_cast<float4*>(out + (size_t)(T - 1) * (NB * O) +
                                 (size_t)b * O + (w - 4) * 16 + lg * 4) = yv;
    }
  }
}

}  // namespace

extern "C" void kernel_launch(void* const* d_in, const int* in_sizes, int n_in,
                              void* d_out, int out_size, void* d_ws, size_t ws_size,
                              hipStream_t stream) {
  const float* xin = (const float*)d_in[0];
  const float* Wih = (const float*)d_in[1];
  const float* Whh = (const float*)d_in[2];
  const float* Who = (const float*)d_in[3];
  float* out = (float*)d_out;
  hipLaunchKernelGGL(rnn_mfma, dim3(NB), dim3(512), 0, stream,
                     xin, Wih, Whh, Who, out);
}